// Round 1
// baseline (262.991 us; speedup 1.0000x reference)
//
#include <hip/hip_runtime.h>
#include <math.h>

// FastLearnableEMA: y[b,t,c] = cumsum_t(x * w) / max(a^t, 1e-8)
//   a = clamp(sigmoid(logit_alpha), 1e-4, 1-1e-4)      [C]
//   w[t] = a^t * (t==0 ? 1 : (1-a))
// B=32, T=2048, C=512, fp32 in/out. Memory-bound (268 MB min traffic).
//
// Block-local two-phase scan. v2 layout: block = 1024 threads covering
// (one b, 32 channels) x 32 t-chunks of 64 steps. Grid = 512 blocks
// -> 2 blocks/CU (32 waves/CU, the full wave budget) so the
// __syncthreads() between phases never idles a CU and read-phase /
// write-phase overlap across the co-resident blocks.
// Phase 1: per-chunk weighted sums -> LDS. Phase 2: exclusive scan of
// chunk sums + re-scan emitting y (re-read hits Infinity Cache; y is
// stored nontemporal so it doesn't evict x from LLC).

#define B_ 32
#define T_ 2048
#define C_ 512
#define NCHUNK 32             // t-chunks per block
#define TCHUNK (T_ / NCHUNK)  // 64
#define CPB 32                // channels per block

__global__ __launch_bounds__(1024, 8)
void ema_scan_kernel(const float* __restrict__ x,
                     const float* __restrict__ logit_alpha,
                     float* __restrict__ y) {
    __shared__ float csum[NCHUNK][CPB];   // 4 KB

    const int tid = threadIdx.x;
    const int cl  = tid & (CPB - 1);      // channel within block
    const int tc  = tid >> 5;             // t-chunk index 0..31
    const int b   = blockIdx.x >> 4;      // C_/CPB == 16 channel groups
    const int cg  = blockIdx.x & 15;
    const int c   = (cg << 5) + cl;

    // per-channel alpha (computed redundantly per t-chunk row; trivial cost)
    const float z = logit_alpha[c];
    float a = 1.0f / (1.0f + expf(-z));
    a = fminf(fmaxf(a, 1e-4f), 1.0f - 1e-4f);
    const float oma = 1.0f - a;

    const int t0 = tc * TCHUNK;
    const float l2a = log2f(a);
    const float ap0 = exp2f((float)t0 * l2a);   // a^t0 (0 on underflow — ok,
                                                // those weights are <1e-38)

    const float* __restrict__ xp = x + ((size_t)b * T_ + t0) * C_ + c;
    float* __restrict__ yp       = y + ((size_t)b * T_ + t0) * C_ + c;

    // ---- phase 1: per-chunk weighted sum (last chunk's sum never consumed)
    if (tc < NCHUNK - 1) {
        float ap = ap0;
        float s  = 0.0f;
        #pragma unroll 8
        for (int i = 0; i < TCHUNK; ++i) {
            float w = (t0 + i == 0) ? 1.0f : ap * oma;
            s = fmaf(xp[(size_t)i * C_], w, s);
            ap *= a;
        }
        csum[tc][cl] = s;
    }
    __syncthreads();

    // ---- tiny exclusive scan of chunk sums (<=31 LDS reads/adds per lane)
    float S = 0.0f;
    for (int w2 = 0; w2 < tc; ++w2) S += csum[w2][cl];

    // ---- phase 2: re-scan chunk, emit y
    // 1/max(a^t,1e-8) == min(a^-t, 1e8): a^-t via recurrence; overflow->inf
    // is clamped to 1e8, matching the reference's EPS clamp exactly.
    float ap    = ap0;
    const float inva = 1.0f / a;
    float invap = exp2f(-(float)t0 * l2a);
    #pragma unroll 8
    for (int i = 0; i < TCHUNK; ++i) {
        float w = (t0 + i == 0) ? 1.0f : ap * oma;
        S = fmaf(xp[(size_t)i * C_], w, S);
        const float invd = fminf(invap, 1e8f);
        __builtin_nontemporal_store(S * invd, &yp[(size_t)i * C_]);
        ap    *= a;
        invap *= inva;
    }
}

extern "C" void kernel_launch(void* const* d_in, const int* in_sizes, int n_in,
                              void* d_out, int out_size, void* d_ws, size_t ws_size,
                              hipStream_t stream) {
    const float* x  = (const float*)d_in[0];   // [32, 2048, 512] fp32
    const float* la = (const float*)d_in[1];   // [512] fp32
    float* y = (float*)d_out;                  // [32, 2048, 512] fp32

    dim3 grid(B_ * (C_ / CPB));   // 512 blocks -> 2 blocks/CU
    dim3 block(1024);             // 16 waves
    hipLaunchKernelGGL(ema_scan_kernel, grid, block, 0, stream, x, la, y);
}